// Round 1
// baseline (393.235 us; speedup 1.0000x reference)
//
#include <hip/hip_runtime.h>

#define HH 512
#define FF 2048
#define BB 16
#define SS 2048
#define MM 32768  // BB*SS

using f32x4 = __attribute__((ext_vector_type(4))) float;
using s16x8 = __attribute__((ext_vector_type(8))) short;

struct __align__(8)  US4 { unsigned short x, y, z, w; };
struct __align__(16) US8 { unsigned short s[8]; };

__device__ __forceinline__ unsigned short f2bf(float f) {
  unsigned int u = __builtin_bit_cast(unsigned int, f);
  u += 0x7fffu + ((u >> 16) & 1u);
  return (unsigned short)(u >> 16);
}
__device__ __forceinline__ float bf2f(unsigned short u) {
  unsigned int x = ((unsigned int)u) << 16;
  return __builtin_bit_cast(float, x);
}
__device__ __forceinline__ void gload_lds16(const void* g, void* l) {
  __builtin_amdgcn_global_load_lds(
      (const __attribute__((address_space(1))) unsigned int*)g,
      (__attribute__((address_space(3))) unsigned int*)l, 16, 0, 0);
}

// ---- weight conversions ----
__global__ void k_conv_we(const float* __restrict__ W, unsigned short* __restrict__ O) {
  int idx = blockIdx.x * 256 + threadIdx.x;  // < 262144
  f32x4 x = *(const f32x4*)(W + idx * 4);
  US4 p{f2bf(x.x), f2bf(x.y), f2bf(x.z), f2bf(x.w)};
  *(US4*)(O + idx * 4) = p;
}
__global__ void k_conv_wae(const float* __restrict__ Wa, unsigned short* __restrict__ O) {
  int idx = blockIdx.x * 256 + threadIdx.x;  // < 65536
  int k = idx >> 7, h4 = idx & 127;
  f32x4 x = *(const f32x4*)(Wa + k * 1024 + 512 + h4 * 4);
  US4 p{f2bf(x.x), f2bf(x.y), f2bf(x.z), f2bf(x.w)};
  *(US4*)(O + idx * 4) = p;
}

// ---- h = hidden[-1] @ Wh.T + bh : one wave per output (b,j) ----
__global__ void k_h(const float* __restrict__ hidden, const float* __restrict__ Wh,
                    const float* __restrict__ bh, float* __restrict__ h_ws) {
  int t = threadIdx.x, lane = t & 63, wid = t >> 6;
  int out = blockIdx.x * 4 + wid;  // < 8192
  int b = out >> 9, j = out & 511;
  const float* hr = hidden + (1) * BB * FF + b * FF;  // hidden[-1]
  const float* wr = Wh + j * FF;
  float a = 0.f;
#pragma unroll
  for (int i = 0; i < 8; ++i) {
    int o = i * 256 + lane * 4;
    f32x4 x = *(const f32x4*)(hr + o);
    f32x4 y = *(const f32x4*)(wr + o);
    a += x.x * y.x + x.y * y.y + x.z * y.z + x.w * y.w;
  }
#pragma unroll
  for (int m = 32; m; m >>= 1) a += __shfl_xor(a, m);
  if (lane == 0) h_ws[out] = a + bh[j];
}

// ---- bb[b][k] = ba[k] + h[b] . Wa[k, 0:512] : one wave per output ----
__global__ void k_bb(const float* __restrict__ h_ws, const float* __restrict__ Wa,
                     const float* __restrict__ ba, float* __restrict__ bb_ws) {
  int t = threadIdx.x, lane = t & 63, wid = t >> 6;
  int out = blockIdx.x * 4 + wid;  // < 8192
  int b = out >> 9, k = out & 511;
  const float* hr = h_ws + b * HH;
  const float* wa = Wa + k * 1024;
  float a = 0.f;
#pragma unroll
  for (int i = 0; i < 2; ++i) {
    int o = i * 256 + lane * 4;
    f32x4 x = *(const f32x4*)(hr + o);
    f32x4 y = *(const f32x4*)(wa + o);
    a += x.x * y.x + x.y * y.y + x.z * y.z + x.w * y.w;
  }
#pragma unroll
  for (int m = 32; m; m >>= 1) a += __shfl_xor(a, m);
  if (lane == 0) bb_ws[out] = a + ba[k];
}

// ---- GEMM1: eo = bf16(enc) @ We_bf16^T + be  -> bf16 store ----
__global__ __launch_bounds__(256, 2) void k_gemm1(
    const float* __restrict__ enc, const unsigned short* __restrict__ Web,
    const float* __restrict__ be, unsigned short* __restrict__ eo) {
  __shared__ unsigned short smem[128 * 64 * 2];  // As | Bs, 32KB
  unsigned short* As = smem;
  unsigned short* Bs = smem + 128 * 64;
  const int t = threadIdx.x, lane = t & 63;
  const int wid = t >> 6, wr = wid >> 1, wc = wid & 1;
  const int bid = blockIdx.x;
  const int n0 = (bid & 3) * 128;
  const int m0 = (bid >> 2) * 128;
  f32x4 acc[4][4] = {};

#pragma unroll 1
  for (int kt = 0; kt < FF; kt += 64) {
    // B tile (We rows n0..n0+127, k kt..kt+63) async -> LDS
#pragma unroll
    for (int i = 0; i < 4; ++i) {
      int idx = i * 256 + t;
      int row = idx >> 3, c = idx & 7;
      gload_lds16(Web + (n0 + row) * FF + kt + c * 8, Bs + idx * 8);
    }
    // A tile: f32 load + cvt -> bf16 LDS
#pragma unroll
    for (int i = 0; i < 8; ++i) {
      int idx = i * 256 + t;
      int row = idx >> 4, c = idx & 15;
      f32x4 x = *(const f32x4*)(enc + (m0 + row) * FF + kt + c * 4);
      US4 p{f2bf(x.x), f2bf(x.y), f2bf(x.z), f2bf(x.w)};
      *(US4*)(As + idx * 4) = p;
    }
    __syncthreads();
#pragma unroll
    for (int ks = 0; ks < 2; ++ks) {
      s16x8 af[4], bfr[4];
#pragma unroll
      for (int mi = 0; mi < 4; ++mi)
        af[mi] = *(const s16x8*)(As + (wr * 64 + mi * 16 + (lane & 15)) * 64 + ks * 32 + (lane >> 4) * 8);
#pragma unroll
      for (int ni = 0; ni < 4; ++ni)
        bfr[ni] = *(const s16x8*)(Bs + (wc * 64 + ni * 16 + (lane & 15)) * 64 + ks * 32 + (lane >> 4) * 8);
#pragma unroll
      for (int mi = 0; mi < 4; ++mi)
#pragma unroll
        for (int ni = 0; ni < 4; ++ni)
          acc[mi][ni] = __builtin_amdgcn_mfma_f32_16x16x32_bf16(af[mi], bfr[ni], acc[mi][ni], 0, 0, 0);
    }
    __syncthreads();
  }

  // epilogue: +be, cvt bf16, repack via LDS, coalesced 16B stores
  unsigned short* Cs = smem;  // 128x128 ushort = 32KB
#pragma unroll
  for (int ni = 0; ni < 4; ++ni) {
    int col = wc * 64 + ni * 16 + (lane & 15);
    float bev = be[n0 + col];
#pragma unroll
    for (int mi = 0; mi < 4; ++mi) {
      int row = wr * 64 + mi * 16 + (lane >> 4) * 4;
#pragma unroll
      for (int j = 0; j < 4; ++j)
        Cs[(row + j) * 128 + col] = f2bf(acc[mi][ni][j] + bev);
    }
  }
  __syncthreads();
#pragma unroll
  for (int i = 0; i < 8; ++i) {
    int idx = i * 256 + t;  // 2048 groups of 8 ushorts
    int row = idx >> 4, c = idx & 15;
    *(US8*)(eo + (m0 + row) * HH + n0 + c * 8) = *(const US8*)(Cs + row * 128 + c * 8);
  }
}

// ---- GEMM2 + tanh + v-dot: partial scores per 128-col chunk ----
__global__ __launch_bounds__(256, 2) void k_gemm2(
    const unsigned short* __restrict__ eo, const unsigned short* __restrict__ Waeb,
    const float* __restrict__ bbw, const float* __restrict__ vv,
    float* __restrict__ sp) {
  __shared__ unsigned short smem[128 * 64 * 2];
  __shared__ float part[2][128];
  unsigned short* As = smem;
  unsigned short* Bs = smem + 128 * 64;
  const int t = threadIdx.x, lane = t & 63;
  const int wid = t >> 6, wr = wid >> 1, wc = wid & 1;
  const int bid = blockIdx.x;
  const int n0 = (bid & 3) * 128;
  const int m0 = (bid >> 2) * 128;
  const int b = m0 >> 11;
  f32x4 acc[4][4] = {};

#pragma unroll 1
  for (int kt = 0; kt < HH; kt += 64) {
#pragma unroll
    for (int i = 0; i < 4; ++i) {
      int idx = i * 256 + t;
      int row = idx >> 3, c = idx & 7;
      gload_lds16(eo + (m0 + row) * HH + kt + c * 8, As + idx * 8);
    }
#pragma unroll
    for (int i = 0; i < 4; ++i) {
      int idx = i * 256 + t;
      int row = idx >> 3, c = idx & 7;
      gload_lds16(Waeb + (n0 + row) * HH + kt + c * 8, Bs + idx * 8);
    }
    __syncthreads();
#pragma unroll
    for (int ks = 0; ks < 2; ++ks) {
      s16x8 af[4], bfr[4];
#pragma unroll
      for (int mi = 0; mi < 4; ++mi)
        af[mi] = *(const s16x8*)(As + (wr * 64 + mi * 16 + (lane & 15)) * 64 + ks * 32 + (lane >> 4) * 8);
#pragma unroll
      for (int ni = 0; ni < 4; ++ni)
        bfr[ni] = *(const s16x8*)(Bs + (wc * 64 + ni * 16 + (lane & 15)) * 64 + ks * 32 + (lane >> 4) * 8);
#pragma unroll
      for (int mi = 0; mi < 4; ++mi)
#pragma unroll
        for (int ni = 0; ni < 4; ++ni)
          acc[mi][ni] = __builtin_amdgcn_mfma_f32_16x16x32_bf16(af[mi], bfr[ni], acc[mi][ni], 0, 0, 0);
    }
    __syncthreads();
  }

  // epilogue: tanh(E + bb) . v over this block's 128 cols
  float vcol[4], bcol[4];
#pragma unroll
  for (int ni = 0; ni < 4; ++ni) {
    int col = n0 + wc * 64 + ni * 16 + (lane & 15);
    vcol[ni] = vv[col];
    bcol[ni] = bbw[b * HH + col];
  }
  float ps[4][4];
#pragma unroll
  for (int mi = 0; mi < 4; ++mi)
#pragma unroll
    for (int j = 0; j < 4; ++j) {
      float s = 0.f;
#pragma unroll
      for (int ni = 0; ni < 4; ++ni)
        s += tanhf(acc[mi][ni][j] + bcol[ni]) * vcol[ni];
      ps[mi][j] = s;
    }
#pragma unroll
  for (int m = 1; m < 16; m <<= 1)
#pragma unroll
    for (int mi = 0; mi < 4; ++mi)
#pragma unroll
      for (int j = 0; j < 4; ++j) ps[mi][j] += __shfl_xor(ps[mi][j], m);
  if ((lane & 15) == 0) {
#pragma unroll
    for (int mi = 0; mi < 4; ++mi)
#pragma unroll
      for (int j = 0; j < 4; ++j)
        part[wc][wr * 64 + mi * 16 + (lane >> 4) * 4 + j] = ps[mi][j];
  }
  __syncthreads();
  if (t < 128) sp[(bid & 3) * MM + m0 + t] = part[0][t] + part[1][t];
}

// ---- reduce partials + softmax over S per batch ----
__global__ void k_softmax(const float* __restrict__ sp, float* __restrict__ attn) {
  const int b = blockIdx.x, t = threadIdx.x, lane = t & 63, wid = t >> 6;
  __shared__ float red[4];
  float vals[8], lmax = -3.0e38f;
#pragma unroll
  for (int i = 0; i < 8; ++i) {
    int s = t + i * 256;
    float x = sp[b * SS + s] + sp[MM + b * SS + s] + sp[2 * MM + b * SS + s] + sp[3 * MM + b * SS + s];
    vals[i] = x;
    lmax = fmaxf(lmax, x);
  }
#pragma unroll
  for (int m = 32; m; m >>= 1) lmax = fmaxf(lmax, __shfl_xor(lmax, m));
  if (lane == 0) red[wid] = lmax;
  __syncthreads();
  lmax = fmaxf(fmaxf(red[0], red[1]), fmaxf(red[2], red[3]));
  __syncthreads();
  float lsum = 0.f;
#pragma unroll
  for (int i = 0; i < 8; ++i) {
    vals[i] = __expf(vals[i] - lmax);
    lsum += vals[i];
  }
#pragma unroll
  for (int m = 32; m; m >>= 1) lsum += __shfl_xor(lsum, m);
  if (lane == 0) red[wid] = lsum;
  __syncthreads();
  float inv = 1.0f / (red[0] + red[1] + red[2] + red[3]);
#pragma unroll
  for (int i = 0; i < 8; ++i) attn[b * SS + t + i * 256] = vals[i] * inv;
}

// ---- context stage 1: partial sums over 256-row s-chunks ----
__global__ __launch_bounds__(512) void k_ctx1(const unsigned short* __restrict__ eo,
                                              const float* __restrict__ attn,
                                              float* __restrict__ cp) {
  const int b = blockIdx.x >> 3, ch = blockIdx.x & 7, h = threadIdx.x;
  const float* aw = attn + b * SS + ch * 256;
  const unsigned short* ep = eo + (b * SS + ch * 256) * HH + h;
  float a = 0.f;
  for (int s = 0; s < 256; ++s) a += aw[s] * bf2f(ep[s * HH]);
  cp[blockIdx.x * HH + h] = a;
}

// ---- context stage 2 ----
__global__ void k_ctx2(const float* __restrict__ cp, float* __restrict__ ctx) {
  const int b = blockIdx.x, h = threadIdx.x;
  float a = 0.f;
#pragma unroll
  for (int c = 0; c < 8; ++c) a += cp[(b * 8 + c) * HH + h];
  ctx[b * HH + h] = a;
}

extern "C" void kernel_launch(void* const* d_in, const int* in_sizes, int n_in,
                              void* d_out, int out_size, void* d_ws, size_t ws_size,
                              hipStream_t stream) {
  (void)in_sizes; (void)n_in; (void)out_size; (void)ws_size;
  const float* hidden = (const float*)d_in[0];
  const float* enc    = (const float*)d_in[1];
  const float* We     = (const float*)d_in[2];
  const float* be     = (const float*)d_in[3];
  const float* Wh     = (const float*)d_in[4];
  const float* bh     = (const float*)d_in[5];
  const float* Wa     = (const float*)d_in[6];
  const float* ba     = (const float*)d_in[7];
  const float* v      = (const float*)d_in[8];

  float* out  = (float*)d_out;
  float* ctx  = out;            // 16*512
  float* attn = out + BB * HH;  // 16*2048

  char* ws = (char*)d_ws;
  unsigned short* Web  = (unsigned short*)ws;  ws += (size_t)HH * FF * 2;   // 2 MB
  unsigned short* Waeb = (unsigned short*)ws;  ws += (size_t)HH * HH * 2;   // 512 KB
  float* h_ws  = (float*)ws;                   ws += (size_t)BB * HH * 4;   // 32 KB
  float* bb_ws = (float*)ws;                   ws += (size_t)BB * HH * 4;   // 32 KB
  unsigned short* eo = (unsigned short*)ws;    ws += (size_t)MM * HH * 2;   // 32 MB
  float* sp = (float*)ws;                      ws += (size_t)4 * MM * 4;    // 512 KB
  float* cp = (float*)ws;                      ws += (size_t)BB * 8 * HH * 4; // 256 KB

  k_conv_we<<<1024, 256, 0, stream>>>(We, Web);
  k_conv_wae<<<256, 256, 0, stream>>>(Wa, Waeb);
  k_h<<<2048, 256, 0, stream>>>(hidden, Wh, bh, h_ws);
  k_bb<<<2048, 256, 0, stream>>>(h_ws, Wa, ba, bb_ws);
  k_gemm1<<<1024, 256, 0, stream>>>(enc, Web, be, eo);
  k_gemm2<<<1024, 256, 0, stream>>>(eo, Waeb, bb_ws, v, sp);
  k_softmax<<<16, 256, 0, stream>>>(sp, attn);
  k_ctx1<<<128, 512, 0, stream>>>(eo, attn, cp);
  k_ctx2<<<16, 512, 0, stream>>>(cp, ctx);
}

// Round 3
// 179.126 us; speedup vs baseline: 2.1953x; 2.1953x over previous
//
#include <hip/hip_runtime.h>

#define HH 512
#define FF 2048
#define BB 16
#define SS 2048
#define MM 32768  // BB*SS

using f32x4 = __attribute__((ext_vector_type(4))) float;
using s16x8 = __attribute__((ext_vector_type(8))) short;

struct __align__(8)  US4 { unsigned short x, y, z, w; };
struct __align__(16) US8 { unsigned short s[8]; };

__device__ __forceinline__ unsigned short f2bf(float f) {
  unsigned int u = __builtin_bit_cast(unsigned int, f);
  u += 0x7fffu + ((u >> 16) & 1u);
  return (unsigned short)(u >> 16);
}
__device__ __forceinline__ float bf2f(unsigned short u) {
  unsigned int x = ((unsigned int)u) << 16;
  return __builtin_bit_cast(float, x);
}
__device__ __forceinline__ void gload_lds16(const void* g, void* l) {
  __builtin_amdgcn_global_load_lds(
      (const __attribute__((address_space(1))) unsigned int*)g,
      (__attribute__((address_space(3))) unsigned int*)l, 16, 0, 0);
}

// ---- weight conversions ----
__global__ void k_conv_we(const float* __restrict__ W, unsigned short* __restrict__ O) {
  int idx = blockIdx.x * 256 + threadIdx.x;  // < 262144
  f32x4 x = *(const f32x4*)(W + idx * 4);
  US4 p{f2bf(x.x), f2bf(x.y), f2bf(x.z), f2bf(x.w)};
  *(US4*)(O + idx * 4) = p;
}
__global__ void k_conv_wae(const float* __restrict__ Wa, unsigned short* __restrict__ O) {
  int idx = blockIdx.x * 256 + threadIdx.x;  // < 65536
  int k = idx >> 7, h4 = idx & 127;
  f32x4 x = *(const f32x4*)(Wa + k * 1024 + 512 + h4 * 4);
  US4 p{f2bf(x.x), f2bf(x.y), f2bf(x.z), f2bf(x.w)};
  *(US4*)(O + idx * 4) = p;
}

// ---- h = hidden[-1] @ Wh.T + bh : one wave per output (b,j) ----
__global__ void k_h(const float* __restrict__ hidden, const float* __restrict__ Wh,
                    const float* __restrict__ bh, float* __restrict__ h_ws) {
  int t = threadIdx.x, lane = t & 63, wid = t >> 6;
  int out = blockIdx.x * 4 + wid;  // < 8192
  int b = out >> 9, j = out & 511;
  const float* hr = hidden + (1) * BB * FF + b * FF;  // hidden[-1]
  const float* wr = Wh + j * FF;
  float a = 0.f;
#pragma unroll
  for (int i = 0; i < 8; ++i) {
    int o = i * 256 + lane * 4;
    f32x4 x = *(const f32x4*)(hr + o);
    f32x4 y = *(const f32x4*)(wr + o);
    a += x.x * y.x + x.y * y.y + x.z * y.z + x.w * y.w;
  }
#pragma unroll
  for (int m = 32; m; m >>= 1) a += __shfl_xor(a, m);
  if (lane == 0) h_ws[out] = a + bh[j];
}

// ---- bb[b][k] = ba[k] + h[b] . Wa[k, 0:512] ----
__global__ void k_bb(const float* __restrict__ h_ws, const float* __restrict__ Wa,
                     const float* __restrict__ ba, float* __restrict__ bb_ws) {
  int t = threadIdx.x, lane = t & 63, wid = t >> 6;
  int out = blockIdx.x * 4 + wid;  // < 8192
  int b = out >> 9, k = out & 511;
  const float* hr = h_ws + b * HH;
  const float* wa = Wa + k * 1024;
  float a = 0.f;
#pragma unroll
  for (int i = 0; i < 2; ++i) {
    int o = i * 256 + lane * 4;
    f32x4 x = *(const f32x4*)(hr + o);
    f32x4 y = *(const f32x4*)(wa + o);
    a += x.x * y.x + x.y * y.y + x.z * y.z + x.w * y.w;
  }
#pragma unroll
  for (int m = 32; m; m >>= 1) a += __shfl_xor(a, m);
  if (lane == 0) bb_ws[out] = a + ba[k];
}

// ---- GEMM1: eo = bf16(enc) @ We_bf16^T + be  -> bf16 store ----
// Block: M=64 x N=512 (full N => enc read once). 512 threads, 8 waves,
// wave-tile 64x64. BK=64. LDS: As 8KB + Bs 64KB = 72KB (2 blocks/CU).
// XOR-swizzle: 16B chunk index ^= (row&7); pre-swizzled global source for
// gload_lds (rule 21), direct swizzled ds_write for reg-staged A.
__global__ __launch_bounds__(512, 4) void k_gemm1(
    const float* __restrict__ enc, const unsigned short* __restrict__ Web,
    const float* __restrict__ be, unsigned short* __restrict__ eo) {
  __shared__ unsigned short smem[36864];  // 72KB
  unsigned short* As = smem;              // [64][64] swizzled
  unsigned short* Bs = smem + 4096;       // [512][64] swizzled
  const int t = threadIdx.x, lane = t & 63, wid = t >> 6;
  const int m0 = blockIdx.x * 64;
  f32x4 acc[4][4] = {};

  f32x4 areg[2];
#pragma unroll
  for (int i = 0; i < 2; ++i) {
    int idx = i * 512 + t, row = idx >> 4, c4 = idx & 15;
    areg[i] = *(const f32x4*)(enc + (size_t)(m0 + row) * FF + c4 * 4);
  }

#pragma unroll 1
  for (int kt = 0; kt < FF; kt += 64) {
    // B tile: rows 0..511 of Web, pre-swizzled source chunk
#pragma unroll
    for (int i = 0; i < 8; ++i) {
      int idx = i * 512 + t, row = idx >> 3, c = idx & 7;
      int sc = c ^ (row & 7);
      gload_lds16(Web + (size_t)row * FF + kt + sc * 8, Bs + idx * 8);
    }
    // A tile: cvt prefetched regs -> swizzled ds_write
#pragma unroll
    for (int i = 0; i < 2; ++i) {
      int idx = i * 512 + t, row = idx >> 4, c4 = idx & 15;
      f32x4 x = areg[i];
      US4 p{f2bf(x.x), f2bf(x.y), f2bf(x.z), f2bf(x.w)};
      int byte = row * 128 + ((c4 * 8) ^ ((row & 7) << 4));
      *(US4*)((char*)As + byte) = p;
    }
    // prefetch next A
    {
      int ktn = (kt + 64 < FF) ? kt + 64 : 0;
#pragma unroll
      for (int i = 0; i < 2; ++i) {
        int idx = i * 512 + t, row = idx >> 4, c4 = idx & 15;
        areg[i] = *(const f32x4*)(enc + (size_t)(m0 + row) * FF + ktn + c4 * 4);
      }
    }
    __syncthreads();
#pragma unroll
    for (int ks = 0; ks < 2; ++ks) {
      s16x8 af[4], bfr[4];
#pragma unroll
      for (int mi = 0; mi < 4; ++mi) {
        int row = mi * 16 + (lane & 15);
        int byte = row * 128 + ((ks * 64 + (lane >> 4) * 16) ^ ((row & 7) << 4));
        af[mi] = *(const s16x8*)((const char*)As + byte);
      }
#pragma unroll
      for (int ni = 0; ni < 4; ++ni) {
        int row = wid * 64 + ni * 16 + (lane & 15);
        int byte = row * 128 + ((ks * 64 + (lane >> 4) * 16) ^ ((row & 7) << 4));
        bfr[ni] = *(const s16x8*)((const char*)Bs + byte);
      }
#pragma unroll
      for (int mi = 0; mi < 4; ++mi)
#pragma unroll
        for (int ni = 0; ni < 4; ++ni)
          acc[mi][ni] = __builtin_amdgcn_mfma_f32_16x16x32_bf16(af[mi], bfr[ni], acc[mi][ni], 0, 0, 0);
    }
    __syncthreads();
  }

  // epilogue: +be, cvt bf16, repack via LDS (Cs aliases smem), coalesced 16B stores
  unsigned short* Cs = smem;  // [64][512] ushort = 64KB
#pragma unroll
  for (int ni = 0; ni < 4; ++ni) {
    int col = wid * 64 + ni * 16 + (lane & 15);
    float bev = be[col];
#pragma unroll
    for (int mi = 0; mi < 4; ++mi)
#pragma unroll
      for (int j = 0; j < 4; ++j) {
        int row = mi * 16 + (lane >> 4) * 4 + j;
        Cs[row * 512 + col] = f2bf(acc[mi][ni][j] + bev);
      }
  }
  __syncthreads();
#pragma unroll
  for (int i = 0; i < 8; ++i) {
    int idx = i * 512 + t, row = idx >> 6, c = idx & 63;
    *(US8*)(eo + (size_t)(m0 + row) * HH + c * 8) = *(const US8*)(Cs + row * 512 + c * 8);
  }
}

// ---- GEMM2 + tanh + v-dot: partial scores per 128-col chunk ----
__global__ __launch_bounds__(256, 2) void k_gemm2(
    const unsigned short* __restrict__ eo, const unsigned short* __restrict__ Waeb,
    const float* __restrict__ bbw, const float* __restrict__ vv,
    float* __restrict__ sp) {
  __shared__ unsigned short smem[128 * 64 * 2];
  __shared__ float part[2][128];
  unsigned short* As = smem;
  unsigned short* Bs = smem + 128 * 64;
  const int t = threadIdx.x, lane = t & 63;
  const int wid = t >> 6, wr = wid >> 1, wc = wid & 1;
  const int bid = blockIdx.x;
  const int n0 = (bid & 3) * 128;
  const int m0 = (bid >> 2) * 128;
  const int b = m0 >> 11;
  f32x4 acc[4][4] = {};

#pragma unroll 1
  for (int kt = 0; kt < HH; kt += 64) {
#pragma unroll
    for (int i = 0; i < 4; ++i) {
      int idx = i * 256 + t, row = idx >> 3, c = idx & 7;
      int sc = c ^ (row & 7);
      gload_lds16(eo + (size_t)(m0 + row) * HH + kt + sc * 8, As + idx * 8);
    }
#pragma unroll
    for (int i = 0; i < 4; ++i) {
      int idx = i * 256 + t, row = idx >> 3, c = idx & 7;
      int sc = c ^ (row & 7);
      gload_lds16(Waeb + (size_t)(n0 + row) * HH + kt + sc * 8, Bs + idx * 8);
    }
    __syncthreads();
#pragma unroll
    for (int ks = 0; ks < 2; ++ks) {
      s16x8 af[4], bfr[4];
#pragma unroll
      for (int mi = 0; mi < 4; ++mi) {
        int row = wr * 64 + mi * 16 + (lane & 15);
        int byte = row * 128 + ((ks * 64 + (lane >> 4) * 16) ^ ((row & 7) << 4));
        af[mi] = *(const s16x8*)((const char*)As + byte);
      }
#pragma unroll
      for (int ni = 0; ni < 4; ++ni) {
        int row = wc * 64 + ni * 16 + (lane & 15);
        int byte = row * 128 + ((ks * 64 + (lane >> 4) * 16) ^ ((row & 7) << 4));
        bfr[ni] = *(const s16x8*)((const char*)Bs + byte);
      }
#pragma unroll
      for (int mi = 0; mi < 4; ++mi)
#pragma unroll
        for (int ni = 0; ni < 4; ++ni)
          acc[mi][ni] = __builtin_amdgcn_mfma_f32_16x16x32_bf16(af[mi], bfr[ni], acc[mi][ni], 0, 0, 0);
    }
    __syncthreads();
  }

  // epilogue: tanh(E + bb) . v over this block's 128 cols
  float vcol[4], bcol[4];
#pragma unroll
  for (int ni = 0; ni < 4; ++ni) {
    int col = n0 + wc * 64 + ni * 16 + (lane & 15);
    vcol[ni] = vv[col];
    bcol[ni] = bbw[b * HH + col];
  }
  float ps[4][4];
#pragma unroll
  for (int mi = 0; mi < 4; ++mi)
#pragma unroll
    for (int j = 0; j < 4; ++j) {
      float s = 0.f;
#pragma unroll
      for (int ni = 0; ni < 4; ++ni)
        s += tanhf(acc[mi][ni][j] + bcol[ni]) * vcol[ni];
      ps[mi][j] = s;
    }
#pragma unroll
  for (int m = 1; m < 16; m <<= 1)
#pragma unroll
    for (int mi = 0; mi < 4; ++mi)
#pragma unroll
      for (int j = 0; j < 4; ++j) ps[mi][j] += __shfl_xor(ps[mi][j], m);
  if ((lane & 15) == 0) {
#pragma unroll
    for (int mi = 0; mi < 4; ++mi)
#pragma unroll
      for (int j = 0; j < 4; ++j)
        part[wc][wr * 64 + mi * 16 + (lane >> 4) * 4 + j] = ps[mi][j];
  }
  __syncthreads();
  if (t < 128) sp[(bid & 3) * MM + m0 + t] = part[0][t] + part[1][t];
}

// ---- reduce partials + softmax over S per batch ----
__global__ void k_softmax(const float* __restrict__ sp, float* __restrict__ attn) {
  const int b = blockIdx.x, t = threadIdx.x, lane = t & 63, wid = t >> 6;
  __shared__ float red[4];
  float vals[8], lmax = -3.0e38f;
#pragma unroll
  for (int i = 0; i < 8; ++i) {
    int s = t + i * 256;
    float x = sp[b * SS + s] + sp[MM + b * SS + s] + sp[2 * MM + b * SS + s] + sp[3 * MM + b * SS + s];
    vals[i] = x;
    lmax = fmaxf(lmax, x);
  }
#pragma unroll
  for (int m = 32; m; m >>= 1) lmax = fmaxf(lmax, __shfl_xor(lmax, m));
  if (lane == 0) red[wid] = lmax;
  __syncthreads();
  lmax = fmaxf(fmaxf(red[0], red[1]), fmaxf(red[2], red[3]));
  __syncthreads();
  float lsum = 0.f;
#pragma unroll
  for (int i = 0; i < 8; ++i) {
    vals[i] = __expf(vals[i] - lmax);
    lsum += vals[i];
  }
#pragma unroll
  for (int m = 32; m; m >>= 1) lsum += __shfl_xor(lsum, m);
  if (lane == 0) red[wid] = lsum;
  __syncthreads();
  float inv = 1.0f / (red[0] + red[1] + red[2] + red[3]);
#pragma unroll
  for (int i = 0; i < 8; ++i) attn[b * SS + t + i * 256] = vals[i] * inv;
}

// ---- context stage 1: vectorized partial sums over 256-row s-chunks ----
__global__ __launch_bounds__(512) void k_ctx1(const unsigned short* __restrict__ eo,
                                              const float* __restrict__ attn,
                                              float* __restrict__ cp) {
  __shared__ float red[8][512];
  const int b = blockIdx.x >> 3, ch = blockIdx.x & 7, t = threadIdx.x;
  const int tg = t & 63, sg = t >> 6;
  const float* aw = attn + b * SS + ch * 256;
  float acc[8] = {};
  for (int s = sg; s < 256; s += 8) {
    float w = aw[s];
    US8 vv = *(const US8*)(eo + (size_t)(b * SS + ch * 256 + s) * HH + tg * 8);
#pragma unroll
    for (int j = 0; j < 8; ++j) acc[j] += w * bf2f(vv.s[j]);
  }
#pragma unroll
  for (int j = 0; j < 8; ++j) red[sg][tg * 8 + j] = acc[j];
  __syncthreads();
  float a = 0.f;
#pragma unroll
  for (int g = 0; g < 8; ++g) a += red[g][t];
  cp[blockIdx.x * HH + t] = a;
}

// ---- context stage 2 ----
__global__ void k_ctx2(const float* __restrict__ cp, float* __restrict__ ctx) {
  const int b = blockIdx.x, h = threadIdx.x;
  float a = 0.f;
#pragma unroll
  for (int c = 0; c < 8; ++c) a += cp[(b * 8 + c) * HH + h];
  ctx[b * HH + h] = a;
}

extern "C" void kernel_launch(void* const* d_in, const int* in_sizes, int n_in,
                              void* d_out, int out_size, void* d_ws, size_t ws_size,
                              hipStream_t stream) {
  (void)in_sizes; (void)n_in; (void)out_size; (void)ws_size;
  const float* hidden = (const float*)d_in[0];
  const float* enc    = (const float*)d_in[1];
  const float* We     = (const float*)d_in[2];
  const float* be     = (const float*)d_in[3];
  const float* Wh     = (const float*)d_in[4];
  const float* bh     = (const float*)d_in[5];
  const float* Wa     = (const float*)d_in[6];
  const float* ba     = (const float*)d_in[7];
  const float* v      = (const float*)d_in[8];

  float* out  = (float*)d_out;
  float* ctx  = out;            // 16*512
  float* attn = out + BB * HH;  // 16*2048

  char* ws = (char*)d_ws;
  unsigned short* Web  = (unsigned short*)ws;  ws += (size_t)HH * FF * 2;   // 2 MB
  unsigned short* Waeb = (unsigned short*)ws;  ws += (size_t)HH * HH * 2;   // 512 KB
  float* h_ws  = (float*)ws;                   ws += (size_t)BB * HH * 4;   // 32 KB
  float* bb_ws = (float*)ws;                   ws += (size_t)BB * HH * 4;   // 32 KB
  unsigned short* eo = (unsigned short*)ws;    ws += (size_t)MM * HH * 2;   // 32 MB
  float* sp = (float*)ws;                      ws += (size_t)4 * MM * 4;    // 512 KB
  float* cp = (float*)ws;                      ws += (size_t)BB * 8 * HH * 4; // 256 KB

  k_conv_we<<<1024, 256, 0, stream>>>(We, Web);
  k_conv_wae<<<256, 256, 0, stream>>>(Wa, Waeb);
  k_h<<<2048, 256, 0, stream>>>(hidden, Wh, bh, h_ws);
  k_bb<<<2048, 256, 0, stream>>>(h_ws, Wa, ba, bb_ws);
  k_gemm1<<<512, 512, 0, stream>>>(enc, Web, be, eo);
  k_gemm2<<<1024, 256, 0, stream>>>(eo, Waeb, bb_ws, v, sp);
  k_softmax<<<16, 256, 0, stream>>>(sp, attn);
  k_ctx1<<<128, 512, 0, stream>>>(eo, attn, cp);
  k_ctx2<<<16, 512, 0, stream>>>(cp, ctx);
}